// Round 1
// baseline (424.372 us; speedup 1.0000x reference)
//
#include <hip/hip_runtime.h>

#define IN_F 128
#define HF   128   // H*F
#define NH   4
#define NF   32

// ---------------- GEMM (feat @ W) + el/er epilogue ----------------
// One block = 128 threads computes 8 rows x 128 cols. W stays in L2 (64KB).
__global__ void gat_gemm_el_er(const float* __restrict__ feat,
                               const float* __restrict__ W,
                               const float* __restrict__ attn_l,
                               const float* __restrict__ attn_r,
                               float* __restrict__ feat_src,
                               float* __restrict__ el,
                               float* __restrict__ er,
                               int N) {
    __shared__ float fs[8][IN_F];
    const int col  = threadIdx.x;          // 0..127
    const int row0 = blockIdx.x * 8;
    #pragma unroll
    for (int r = 0; r < 8; ++r) {
        int row = row0 + r;
        fs[r][col] = (row < N) ? feat[row * IN_F + col] : 0.f;
    }
    __syncthreads();
    float acc[8] = {0.f,0.f,0.f,0.f,0.f,0.f,0.f,0.f};
    for (int k = 0; k < IN_F; ++k) {
        float w = W[k * HF + col];
        #pragma unroll
        for (int r = 0; r < 8; ++r) acc[r] += fs[r][k] * w;
    }
    const float al = attn_l[col];
    const float ar = attn_r[col];
    #pragma unroll
    for (int r = 0; r < 8; ++r) {
        int row = row0 + r;
        if (row < N) feat_src[row * HF + col] = acc[r];
        float pl = acc[r] * al;
        float pr = acc[r] * ar;
        // reduce over the 32 lanes of each head (masks <=16 stay in 32-group)
        #pragma unroll
        for (int m = 16; m >= 1; m >>= 1) {
            pl += __shfl_xor(pl, m);
            pr += __shfl_xor(pr, m);
        }
        if ((col & 31) == 0 && row < N) {
            int h = col >> 5;
            el[row * NH + h] = pl;
            er[row * NH + h] = pr;
        }
    }
}

// ---------------- CSR build: histogram -> scan -> scatter ----------------
__global__ void gat_hist(const int* __restrict__ dst, int* __restrict__ count, int E) {
    int e = blockIdx.x * blockDim.x + threadIdx.x;
    if (e < E) atomicAdd(&count[dst[e]], 1);
}

__global__ void gat_scan_block(const int* __restrict__ count,
                               int* __restrict__ excl,
                               int* __restrict__ bsum, int n) {
    __shared__ int buf[256];
    int t = threadIdx.x;
    int i = blockIdx.x * 256 + t;
    int v = (i < n) ? count[i] : 0;
    buf[t] = v;
    __syncthreads();
    for (int off = 1; off < 256; off <<= 1) {
        int x = (t >= off) ? buf[t - off] : 0;
        __syncthreads();
        buf[t] += x;
        __syncthreads();
    }
    if (i < n) excl[i] = buf[t] - v;
    if (t == 255) bsum[blockIdx.x] = buf[255];
}

__global__ void gat_scan_bsums(int* __restrict__ bsum, int nb, int* __restrict__ total) {
    __shared__ int buf[512];
    int t = threadIdx.x;
    int v = (t < nb) ? bsum[t] : 0;
    buf[t] = v;
    __syncthreads();
    for (int off = 1; off < 512; off <<= 1) {
        int x = (t >= off) ? buf[t - off] : 0;
        __syncthreads();
        buf[t] += x;
        __syncthreads();
    }
    if (t < nb) bsum[t] = buf[t] - v;   // exclusive block offsets
    if (t == 511) *total = buf[511];
}

__global__ void gat_scan_add(const int* __restrict__ excl, const int* __restrict__ bsum,
                             const int* __restrict__ total, int* __restrict__ offsets,
                             int* __restrict__ cursor, int n) {
    int i = blockIdx.x * 256 + threadIdx.x;
    if (i < n) {
        int o = excl[i] + bsum[blockIdx.x];
        offsets[i] = o;
        cursor[i]  = o;
    }
    if (i == 0) offsets[n] = *total;
}

__global__ void gat_scatter(const int* __restrict__ src, const int* __restrict__ dst,
                            int* __restrict__ cursor, int* __restrict__ slot, int E) {
    int e = blockIdx.x * blockDim.x + threadIdx.x;
    if (e < E) {
        int p = atomicAdd(&cursor[dst[e]], 1);
        slot[p] = src[e];
    }
}

// ---------------- per-dst-node softmax + weighted aggregation ----------------
// One wave (64 lanes) per node. Lane owns cols (2*lane, 2*lane+1); head = lane>>4.
__global__ void __launch_bounds__(64)
gat_aggregate(const float* __restrict__ feat_src, const float* __restrict__ el,
              const float* __restrict__ er, const int* __restrict__ offsets,
              const int* __restrict__ slot, const float* __restrict__ bias,
              float* __restrict__ out, int N) {
    const int node = blockIdx.x;
    const int lane = threadIdx.x;
    const int start = offsets[node];
    const int end   = offsets[node + 1];

    const float er0 = er[node * NH + 0];
    const float er1 = er[node * NH + 1];
    const float er2 = er[node * NH + 2];
    const float er3 = er[node * NH + 3];

    // pass 1: softmax denominators for all 4 heads (lanes split the edges)
    float d0 = 0.f, d1 = 0.f, d2 = 0.f, d3 = 0.f;
    for (int i = start + lane; i < end; i += 64) {
        int s = slot[i];
        float4 ev = *(const float4*)(el + s * NH);
        float x0 = ev.x + er0; d0 += __expf(fmaxf(x0, 0.2f * x0));
        float x1 = ev.y + er1; d1 += __expf(fmaxf(x1, 0.2f * x1));
        float x2 = ev.z + er2; d2 += __expf(fmaxf(x2, 0.2f * x2));
        float x3 = ev.w + er3; d3 += __expf(fmaxf(x3, 0.2f * x3));
    }
    #pragma unroll
    for (int m = 32; m >= 1; m >>= 1) {
        d0 += __shfl_xor(d0, m);
        d1 += __shfl_xor(d1, m);
        d2 += __shfl_xor(d2, m);
        d3 += __shfl_xor(d3, m);
    }

    const int h = lane >> 4;   // col = 2*lane -> head = (2*lane)>>5
    const float er_h = (h == 0) ? er0 : (h == 1) ? er1 : (h == 2) ? er2 : er3;
    const float den  = (h == 0) ? d0  : (h == 1) ? d1  : (h == 2) ? d2  : d3;
    const float inv  = 1.0f / fmaxf(den, 1e-9f);

    // pass 2: weighted aggregation; whole wave walks the edge list together
    float ax = 0.f, ay = 0.f;
    const float* fsp = feat_src + 2 * lane;
    for (int i = start; i < end; ++i) {
        int s = slot[i];
        float eh = el[s * NH + h] + er_h;
        float w  = __expf(fmaxf(eh, 0.2f * eh)) * inv;
        float2 f2 = *(const float2*)(fsp + s * HF);
        ax += w * f2.x;
        ay += w * f2.y;
    }
    float2 b2 = *(const float2*)(bias + 2 * lane);
    out[node * HF + 2 * lane]     = ax + b2.x;
    out[node * HF + 2 * lane + 1] = ay + b2.y;
}

extern "C" void kernel_launch(void* const* d_in, const int* in_sizes, int n_in,
                              void* d_out, int out_size, void* d_ws, size_t ws_size,
                              hipStream_t stream) {
    const float* feat   = (const float*)d_in[0];
    const float* W      = (const float*)d_in[1];
    const float* attn_l = (const float*)d_in[2];
    const float* attn_r = (const float*)d_in[3];
    const float* bias   = (const float*)d_in[4];
    const int*   src    = (const int*)d_in[5];
    const int*   dst    = (const int*)d_in[6];
    float* out = (float*)d_out;

    const int N = in_sizes[0] / IN_F;
    const int E = in_sizes[5];
    const int nb = (N + 255) / 256;

    // workspace carve-up (256B aligned)
    char* ws = (char*)d_ws;
    size_t off = 0;
    auto alloc = [&](size_t bytes) -> void* {
        off = (off + 255) & ~(size_t)255;
        void* p = ws + off;
        off += bytes;
        return p;
    };
    float* feat_src = (float*)alloc((size_t)N * HF * sizeof(float));
    float* el       = (float*)alloc((size_t)N * NH * sizeof(float));
    float* er       = (float*)alloc((size_t)N * NH * sizeof(float));
    int*   count    = (int*)  alloc((size_t)N * sizeof(int));
    int*   excl     = (int*)  alloc((size_t)N * sizeof(int));
    int*   bsum     = (int*)  alloc((size_t)nb * sizeof(int));
    int*   total    = (int*)  alloc(sizeof(int));
    int*   offsets  = (int*)  alloc((size_t)(N + 1) * sizeof(int));
    int*   cursor   = (int*)  alloc((size_t)N * sizeof(int));
    int*   slot     = (int*)  alloc((size_t)E * sizeof(int));

    hipMemsetAsync(count, 0, (size_t)N * sizeof(int), stream);

    gat_gemm_el_er<<<(N + 7) / 8, 128, 0, stream>>>(feat, W, attn_l, attn_r,
                                                    feat_src, el, er, N);
    gat_hist<<<(E + 255) / 256, 256, 0, stream>>>(dst, count, E);
    gat_scan_block<<<nb, 256, 0, stream>>>(count, excl, bsum, N);
    gat_scan_bsums<<<1, 512, 0, stream>>>(bsum, nb, total);
    gat_scan_add<<<nb, 256, 0, stream>>>(excl, bsum, total, offsets, cursor, N);
    gat_scatter<<<(E + 255) / 256, 256, 0, stream>>>(src, dst, cursor, slot, E);
    gat_aggregate<<<N, 64, 0, stream>>>(feat_src, el, er, offsets, slot, bias, out, N);
}

// Round 2
// 377.417 us; speedup vs baseline: 1.1244x; 1.1244x over previous
//
#include <hip/hip_runtime.h>

#define IN_F 128
#define HF   128   // H*F
#define NH   4
#define NF   32
#define GEMM_ROWS 16

// bf16 helpers (bit-level, RTN)
__device__ __forceinline__ unsigned short f32_to_bf16_rtn(float f) {
    unsigned int u = __float_as_uint(f);
    u += 0x7fffu + ((u >> 16) & 1u);
    return (unsigned short)(u >> 16);
}

// ---------------- GEMM (feat @ W) + el/er epilogue ----------------
// One block = 128 threads computes GEMM_ROWS rows x 128 cols.
__global__ void gat_gemm_el_er(const float* __restrict__ feat,
                               const float* __restrict__ W,
                               const float* __restrict__ attn_l,
                               const float* __restrict__ attn_r,
                               unsigned short* __restrict__ feat_src_bf,
                               float* __restrict__ el,
                               float* __restrict__ er,
                               int N) {
    __shared__ float fs[GEMM_ROWS][IN_F];
    const int col  = threadIdx.x;          // 0..127
    const int row0 = blockIdx.x * GEMM_ROWS;
    #pragma unroll
    for (int r = 0; r < GEMM_ROWS; ++r) {
        int row = row0 + r;
        fs[r][col] = (row < N) ? feat[row * IN_F + col] : 0.f;
    }
    __syncthreads();
    float acc[GEMM_ROWS];
    #pragma unroll
    for (int r = 0; r < GEMM_ROWS; ++r) acc[r] = 0.f;
    #pragma unroll 4
    for (int k = 0; k < IN_F; ++k) {
        float w = W[k * HF + col];
        #pragma unroll
        for (int r = 0; r < GEMM_ROWS; ++r) acc[r] += fs[r][k] * w;
    }
    const float al = attn_l[col];
    const float ar = attn_r[col];
    #pragma unroll
    for (int r = 0; r < GEMM_ROWS; ++r) {
        int row = row0 + r;
        if (row < N) feat_src_bf[row * HF + col] = f32_to_bf16_rtn(acc[r]);
        float pl = acc[r] * al;
        float pr = acc[r] * ar;
        // reduce over the 32 lanes of each head (masks <=16 stay in 32-group)
        #pragma unroll
        for (int m = 16; m >= 1; m >>= 1) {
            pl += __shfl_xor(pl, m);
            pr += __shfl_xor(pr, m);
        }
        if ((col & 31) == 0 && row < N) {
            int h = col >> 5;
            el[row * NH + h] = pl;
            er[row * NH + h] = pr;
        }
    }
}

// ---------------- CSR build: histogram -> scan -> scatter ----------------
__global__ void gat_hist(const int* __restrict__ dst, int* __restrict__ count, int E) {
    int e = blockIdx.x * blockDim.x + threadIdx.x;
    if (e < E) atomicAdd(&count[dst[e]], 1);
}

__global__ void gat_scan_block(const int* __restrict__ count,
                               int* __restrict__ excl,
                               int* __restrict__ bsum, int n) {
    __shared__ int buf[256];
    int t = threadIdx.x;
    int i = blockIdx.x * 256 + t;
    int v = (i < n) ? count[i] : 0;
    buf[t] = v;
    __syncthreads();
    for (int off = 1; off < 256; off <<= 1) {
        int x = (t >= off) ? buf[t - off] : 0;
        __syncthreads();
        buf[t] += x;
        __syncthreads();
    }
    if (i < n) excl[i] = buf[t] - v;
    if (t == 255) bsum[blockIdx.x] = buf[255];
}

__global__ void gat_scan_bsums(int* __restrict__ bsum, int nb, int* __restrict__ total) {
    __shared__ int buf[512];
    int t = threadIdx.x;
    int v = (t < nb) ? bsum[t] : 0;
    buf[t] = v;
    __syncthreads();
    for (int off = 1; off < 512; off <<= 1) {
        int x = (t >= off) ? buf[t - off] : 0;
        __syncthreads();
        buf[t] += x;
        __syncthreads();
    }
    if (t < nb) bsum[t] = buf[t] - v;   // exclusive block offsets
    if (t == 511) *total = buf[511];
}

__global__ void gat_scan_add(const int* __restrict__ excl, const int* __restrict__ bsum,
                             const int* __restrict__ total, int* __restrict__ offsets,
                             int* __restrict__ cursor, int n) {
    int i = blockIdx.x * 256 + threadIdx.x;
    if (i < n) {
        int o = excl[i] + bsum[blockIdx.x];
        offsets[i] = o;
        cursor[i]  = o;
    }
    if (i == 0) offsets[n] = *total;
}

__global__ void gat_scatter(const int* __restrict__ src, const int* __restrict__ dst,
                            int* __restrict__ cursor, int* __restrict__ slot, int E) {
    int e = blockIdx.x * blockDim.x + threadIdx.x;
    if (e < E) {
        int p = atomicAdd(&cursor[dst[e]], 1);
        slot[p] = src[e];
    }
}

// ---------------- per-dst-node softmax + weighted aggregation ----------------
// One wave (64 lanes) per node. Lane owns cols (2*lane, 2*lane+1); head = lane>>4.
__global__ void __launch_bounds__(64)
gat_aggregate(const unsigned short* __restrict__ feat_src_bf,
              const float* __restrict__ el,
              const float* __restrict__ er, const int* __restrict__ offsets,
              const int* __restrict__ slot, const float* __restrict__ bias,
              float* __restrict__ out, int N) {
    const int node = blockIdx.x;
    const int lane = threadIdx.x;
    const int start = offsets[node];
    const int end   = offsets[node + 1];

    const float er0 = er[node * NH + 0];
    const float er1 = er[node * NH + 1];
    const float er2 = er[node * NH + 2];
    const float er3 = er[node * NH + 3];

    // pass 1: softmax denominators for all 4 heads (lanes split the edges)
    float d0 = 0.f, d1 = 0.f, d2 = 0.f, d3 = 0.f;
    for (int i = start + lane; i < end; i += 64) {
        int s = slot[i];
        float4 ev = *(const float4*)(el + s * NH);
        float x0 = ev.x + er0; d0 += __expf(fmaxf(x0, 0.2f * x0));
        float x1 = ev.y + er1; d1 += __expf(fmaxf(x1, 0.2f * x1));
        float x2 = ev.z + er2; d2 += __expf(fmaxf(x2, 0.2f * x2));
        float x3 = ev.w + er3; d3 += __expf(fmaxf(x3, 0.2f * x3));
    }
    #pragma unroll
    for (int m = 32; m >= 1; m >>= 1) {
        d0 += __shfl_xor(d0, m);
        d1 += __shfl_xor(d1, m);
        d2 += __shfl_xor(d2, m);
        d3 += __shfl_xor(d3, m);
    }

    const int h = lane >> 4;   // col = 2*lane -> head = (2*lane)>>5
    const float er_h = (h == 0) ? er0 : (h == 1) ? er1 : (h == 2) ? er2 : er3;
    const float den  = (h == 0) ? d0  : (h == 1) ? d1  : (h == 2) ? d2  : d3;
    const float inv  = 1.0f / fmaxf(den, 1e-9f);

    // pass 2: weighted aggregation; whole wave walks the edge list together.
    // 2-way unroll for memory-level parallelism (latency-limited otherwise).
    float ax = 0.f, ay = 0.f;
    const unsigned short* fsp = feat_src_bf + 2 * lane;
    int i = start;
    for (; i + 1 < end; i += 2) {
        int s0 = slot[i];
        int s1 = slot[i + 1];
        float e0 = el[s0 * NH + h] + er_h;
        float e1 = el[s1 * NH + h] + er_h;
        unsigned int u0 = *(const unsigned int*)(fsp + (size_t)s0 * HF);
        unsigned int u1 = *(const unsigned int*)(fsp + (size_t)s1 * HF);
        float w0 = __expf(fmaxf(e0, 0.2f * e0)) * inv;
        float w1 = __expf(fmaxf(e1, 0.2f * e1)) * inv;
        float f0x = __uint_as_float(u0 << 16);
        float f0y = __uint_as_float(u0 & 0xffff0000u);
        float f1x = __uint_as_float(u1 << 16);
        float f1y = __uint_as_float(u1 & 0xffff0000u);
        ax += w0 * f0x + w1 * f1x;
        ay += w0 * f0y + w1 * f1y;
    }
    if (i < end) {
        int s0 = slot[i];
        float e0 = el[s0 * NH + h] + er_h;
        unsigned int u0 = *(const unsigned int*)(fsp + (size_t)s0 * HF);
        float w0 = __expf(fmaxf(e0, 0.2f * e0)) * inv;
        ax += w0 * __uint_as_float(u0 << 16);
        ay += w0 * __uint_as_float(u0 & 0xffff0000u);
    }
    float2 b2 = *(const float2*)(bias + 2 * lane);
    out[node * HF + 2 * lane]     = ax + b2.x;
    out[node * HF + 2 * lane + 1] = ay + b2.y;
}

extern "C" void kernel_launch(void* const* d_in, const int* in_sizes, int n_in,
                              void* d_out, int out_size, void* d_ws, size_t ws_size,
                              hipStream_t stream) {
    const float* feat   = (const float*)d_in[0];
    const float* W      = (const float*)d_in[1];
    const float* attn_l = (const float*)d_in[2];
    const float* attn_r = (const float*)d_in[3];
    const float* bias   = (const float*)d_in[4];
    const int*   src    = (const int*)d_in[5];
    const int*   dst    = (const int*)d_in[6];
    float* out = (float*)d_out;

    const int N = in_sizes[0] / IN_F;
    const int E = in_sizes[5];
    const int nb = (N + 255) / 256;

    // workspace carve-up (256B aligned)
    char* ws = (char*)d_ws;
    size_t off = 0;
    auto alloc = [&](size_t bytes) -> void* {
        off = (off + 255) & ~(size_t)255;
        void* p = ws + off;
        off += bytes;
        return p;
    };
    unsigned short* feat_src_bf = (unsigned short*)alloc((size_t)N * HF * sizeof(unsigned short));
    float* el       = (float*)alloc((size_t)N * NH * sizeof(float));
    float* er       = (float*)alloc((size_t)N * NH * sizeof(float));
    int*   count    = (int*)  alloc((size_t)N * sizeof(int));
    int*   excl     = (int*)  alloc((size_t)N * sizeof(int));
    int*   bsum     = (int*)  alloc((size_t)nb * sizeof(int));
    int*   total    = (int*)  alloc(sizeof(int));
    int*   offsets  = (int*)  alloc((size_t)(N + 1) * sizeof(int));
    int*   cursor   = (int*)  alloc((size_t)N * sizeof(int));
    int*   slot     = (int*)  alloc((size_t)E * sizeof(int));

    hipMemsetAsync(count, 0, (size_t)N * sizeof(int), stream);

    gat_gemm_el_er<<<(N + GEMM_ROWS - 1) / GEMM_ROWS, 128, 0, stream>>>(
        feat, W, attn_l, attn_r, feat_src_bf, el, er, N);
    gat_hist<<<(E + 255) / 256, 256, 0, stream>>>(dst, count, E);
    gat_scan_block<<<nb, 256, 0, stream>>>(count, excl, bsum, N);
    gat_scan_bsums<<<1, 512, 0, stream>>>(bsum, nb, total);
    gat_scan_add<<<nb, 256, 0, stream>>>(excl, bsum, total, offsets, cursor, N);
    gat_scatter<<<(E + 255) / 256, 256, 0, stream>>>(src, dst, cursor, slot, E);
    gat_aggregate<<<N, 64, 0, stream>>>(feat_src_bf, el, er, offsets, slot, bias, out, N);
}

// Round 3
// 232.383 us; speedup vs baseline: 1.8262x; 1.6241x over previous
//
#include <hip/hip_runtime.h>

#define IN_F 128
#define HF   128   // H*F
#define NH   4
#define NF   32
#define GEMM_ROWS 16

#define NPB       256   // nodes per coarse bucket
#define NPB_SHIFT 8
#define BIN_CHUNK 4096  // edges per binning workgroup

// bf16 helpers (bit-level, RTN)
__device__ __forceinline__ unsigned short f32_to_bf16_rtn(float f) {
    unsigned int u = __float_as_uint(f);
    u += 0x7fffu + ((u >> 16) & 1u);
    return (unsigned short)(u >> 16);
}

// ---------------- GEMM (feat @ W) + el/er epilogue ----------------
__global__ void gat_gemm_el_er(const float* __restrict__ feat,
                               const float* __restrict__ W,
                               const float* __restrict__ attn_l,
                               const float* __restrict__ attn_r,
                               unsigned short* __restrict__ feat_src_bf,
                               float* __restrict__ el,
                               float* __restrict__ er,
                               int N) {
    __shared__ float fs[GEMM_ROWS][IN_F];
    const int col  = threadIdx.x;          // 0..127
    const int row0 = blockIdx.x * GEMM_ROWS;
    #pragma unroll
    for (int r = 0; r < GEMM_ROWS; ++r) {
        int row = row0 + r;
        fs[r][col] = (row < N) ? feat[row * IN_F + col] : 0.f;
    }
    __syncthreads();
    float acc[GEMM_ROWS];
    #pragma unroll
    for (int r = 0; r < GEMM_ROWS; ++r) acc[r] = 0.f;
    #pragma unroll 4
    for (int k = 0; k < IN_F; ++k) {
        float w = W[k * HF + col];
        #pragma unroll
        for (int r = 0; r < GEMM_ROWS; ++r) acc[r] += fs[r][k] * w;
    }
    const float al = attn_l[col];
    const float ar = attn_r[col];
    #pragma unroll
    for (int r = 0; r < GEMM_ROWS; ++r) {
        int row = row0 + r;
        if (row < N) feat_src_bf[row * HF + col] = f32_to_bf16_rtn(acc[r]);
        float pl = acc[r] * al;
        float pr = acc[r] * ar;
        #pragma unroll
        for (int m = 16; m >= 1; m >>= 1) {
            pl += __shfl_xor(pl, m);
            pr += __shfl_xor(pr, m);
        }
        if ((col & 31) == 0 && row < N) {
            int h = col >> 5;
            el[row * NH + h] = pl;
            er[row * NH + h] = pr;
        }
    }
}

// ---------------- CSR build via 2-level binning ----------------
// K1: coarse histogram of dst>>NPB_SHIFT
__global__ void __launch_bounds__(256)
gat_bucket_hist(const int* __restrict__ dst, int* __restrict__ bcount,
                int E, int nbuck, int chunk) {
    __shared__ int h[512];
    const int t = threadIdx.x;
    for (int i = t; i < 512; i += 256) h[i] = 0;
    __syncthreads();
    const int e0 = blockIdx.x * chunk;
    const int e1 = min(e0 + chunk, E);
    for (int e = e0 + t; e < e1; e += 256)
        atomicAdd(&h[dst[e] >> NPB_SHIFT], 1);
    __syncthreads();
    for (int b = t; b < nbuck; b += 256)
        if (h[b]) atomicAdd(&bcount[b], h[b]);
}

// K2: single-WG scan of bucket counts (nbuck <= 512)
__global__ void __launch_bounds__(512)
gat_bucket_scan(const int* __restrict__ bcount, int* __restrict__ bbase,
                int* __restrict__ gcursor, int* __restrict__ offsets,
                int N, int E, int nbuck) {
    __shared__ int buf[512];
    const int t = threadIdx.x;
    int v = (t < nbuck) ? bcount[t] : 0;
    buf[t] = v;
    __syncthreads();
    for (int off = 1; off < 512; off <<= 1) {
        int x = (t >= off) ? buf[t - off] : 0;
        __syncthreads();
        buf[t] += x;
        __syncthreads();
    }
    if (t < nbuck) {
        int base = buf[t] - v;
        bbase[t]   = base;
        gcursor[t] = base;
    }
    if (t == 0) {
        bbase[nbuck] = E;
        offsets[N]   = E;
    }
}

// K3: bin (src,dst) pairs into coarse-bucket-contiguous order.
__global__ void __launch_bounds__(256)
gat_bin(const int* __restrict__ src, const int* __restrict__ dst,
        int* __restrict__ gcursor, uint2* __restrict__ gpairs, int E) {
    __shared__ uint2 stage[BIN_CHUNK];        // 32KB
    __shared__ int hist[512];
    __shared__ int sc[512];
    __shared__ int basew[512];
    __shared__ int cur[512];
    const int t = threadIdx.x;
    for (int i = t; i < 512; i += 256) hist[i] = 0;
    __syncthreads();
    const int e0  = blockIdx.x * BIN_CHUNK;
    const int cnt = min(BIN_CHUNK, E - e0);
    // phase 1: chunk histogram by bucket
    for (int i = t; i < cnt; i += 256)
        atomicAdd(&hist[dst[e0 + i] >> NPB_SHIFT], 1);
    __syncthreads();
    // inclusive scan of hist (512 elements, 256 threads, 2 per thread)
    sc[t]       = hist[t];
    sc[t + 256] = hist[t + 256];
    __syncthreads();
    for (int off = 1; off < 512; off <<= 1) {
        int x0 = (t >= off) ? sc[t - off] : 0;
        int x1 = sc[t + 256 - off];
        __syncthreads();
        sc[t]       += x0;
        sc[t + 256] += x1;
        __syncthreads();
    }
    // reserve global ranges; set local cursors to exclusive scan
    for (int b = t; b < 512; b += 256) {
        int c  = hist[b];
        int ex = sc[b] - c;
        cur[b] = ex;
        basew[b] = c ? atomicAdd(&gcursor[b], c) : 0;
    }
    __syncthreads();
    // phase 2: stage pairs in bucket-sorted local order
    for (int i = t; i < cnt; i += 256) {
        unsigned s = (unsigned)src[e0 + i];
        unsigned d = (unsigned)dst[e0 + i];
        int p = atomicAdd(&cur[d >> NPB_SHIFT], 1);
        stage[p] = make_uint2(s, d);
    }
    __syncthreads();
    // phase 3: contiguous-run writeout
    for (int j = t; j < cnt; j += 256) {
        uint2 pr = stage[j];
        int b  = (int)(pr.y >> NPB_SHIFT);
        int ex = sc[b] - hist[b];
        gpairs[basew[b] + (j - ex)] = pr;
    }
}

// K4: per-bucket fine CSR: node offsets + slot scatter (all LDS/L2-local)
__global__ void __launch_bounds__(256)
gat_fine(const uint2* __restrict__ gpairs, const int* __restrict__ bbase,
         int* __restrict__ offsets, int* __restrict__ slot, int N) {
    __shared__ int h[NPB];
    __shared__ int buf[NPB];
    __shared__ int cur[NPB];
    const int b     = blockIdx.x;
    const int node0 = b << NPB_SHIFT;
    const int t     = threadIdx.x;          // 256
    const int beg = bbase[b];
    const int end = bbase[b + 1];
    h[t] = 0;
    __syncthreads();
    for (int i = beg + t; i < end; i += 256)
        atomicAdd(&h[(int)gpairs[i].y - node0], 1);
    __syncthreads();
    int v = h[t];
    buf[t] = v;
    __syncthreads();
    for (int off = 1; off < 256; off <<= 1) {
        int x = (t >= off) ? buf[t - off] : 0;
        __syncthreads();
        buf[t] += x;
        __syncthreads();
    }
    int ex = buf[t] - v;
    if (node0 + t < N) offsets[node0 + t] = beg + ex;
    cur[t] = ex;
    __syncthreads();
    for (int i = beg + t; i < end; i += 256) {
        uint2 pr = gpairs[i];
        int p = atomicAdd(&cur[(int)pr.y - node0], 1);
        slot[beg + p] = (int)pr.x;
    }
}

// ---------------- per-dst-node softmax + weighted aggregation ----------------
__global__ void __launch_bounds__(64)
gat_aggregate(const unsigned short* __restrict__ feat_src_bf,
              const float* __restrict__ el,
              const float* __restrict__ er, const int* __restrict__ offsets,
              const int* __restrict__ slot, const float* __restrict__ bias,
              float* __restrict__ out, int N) {
    const int node = blockIdx.x;
    const int lane = threadIdx.x;
    const int start = offsets[node];
    const int end   = offsets[node + 1];

    const float er0 = er[node * NH + 0];
    const float er1 = er[node * NH + 1];
    const float er2 = er[node * NH + 2];
    const float er3 = er[node * NH + 3];

    float d0 = 0.f, d1 = 0.f, d2 = 0.f, d3 = 0.f;
    for (int i = start + lane; i < end; i += 64) {
        int s = slot[i];
        float4 ev = *(const float4*)(el + s * NH);
        float x0 = ev.x + er0; d0 += __expf(fmaxf(x0, 0.2f * x0));
        float x1 = ev.y + er1; d1 += __expf(fmaxf(x1, 0.2f * x1));
        float x2 = ev.z + er2; d2 += __expf(fmaxf(x2, 0.2f * x2));
        float x3 = ev.w + er3; d3 += __expf(fmaxf(x3, 0.2f * x3));
    }
    #pragma unroll
    for (int m = 32; m >= 1; m >>= 1) {
        d0 += __shfl_xor(d0, m);
        d1 += __shfl_xor(d1, m);
        d2 += __shfl_xor(d2, m);
        d3 += __shfl_xor(d3, m);
    }

    const int h = lane >> 4;
    const float er_h = (h == 0) ? er0 : (h == 1) ? er1 : (h == 2) ? er2 : er3;
    const float den  = (h == 0) ? d0  : (h == 1) ? d1  : (h == 2) ? d2  : d3;
    const float inv  = 1.0f / fmaxf(den, 1e-9f);

    float ax = 0.f, ay = 0.f;
    const unsigned short* fsp = feat_src_bf + 2 * lane;
    int i = start;
    for (; i + 1 < end; i += 2) {
        int s0 = slot[i];
        int s1 = slot[i + 1];
        float e0 = el[s0 * NH + h] + er_h;
        float e1 = el[s1 * NH + h] + er_h;
        unsigned int u0 = *(const unsigned int*)(fsp + (size_t)s0 * HF);
        unsigned int u1 = *(const unsigned int*)(fsp + (size_t)s1 * HF);
        float w0 = __expf(fmaxf(e0, 0.2f * e0)) * inv;
        float w1 = __expf(fmaxf(e1, 0.2f * e1)) * inv;
        ax += w0 * __uint_as_float(u0 << 16) + w1 * __uint_as_float(u1 << 16);
        ay += w0 * __uint_as_float(u0 & 0xffff0000u) + w1 * __uint_as_float(u1 & 0xffff0000u);
    }
    if (i < end) {
        int s0 = slot[i];
        float e0 = el[s0 * NH + h] + er_h;
        unsigned int u0 = *(const unsigned int*)(fsp + (size_t)s0 * HF);
        float w0 = __expf(fmaxf(e0, 0.2f * e0)) * inv;
        ax += w0 * __uint_as_float(u0 << 16);
        ay += w0 * __uint_as_float(u0 & 0xffff0000u);
    }
    float2 b2 = *(const float2*)(bias + 2 * lane);
    out[node * HF + 2 * lane]     = ax + b2.x;
    out[node * HF + 2 * lane + 1] = ay + b2.y;
}

extern "C" void kernel_launch(void* const* d_in, const int* in_sizes, int n_in,
                              void* d_out, int out_size, void* d_ws, size_t ws_size,
                              hipStream_t stream) {
    const float* feat   = (const float*)d_in[0];
    const float* W      = (const float*)d_in[1];
    const float* attn_l = (const float*)d_in[2];
    const float* attn_r = (const float*)d_in[3];
    const float* bias   = (const float*)d_in[4];
    const int*   src    = (const int*)d_in[5];
    const int*   dst    = (const int*)d_in[6];
    float* out = (float*)d_out;

    const int N = in_sizes[0] / IN_F;
    const int E = in_sizes[5];
    const int nbuck = (N + NPB - 1) / NPB;      // 391 for N=100000 (<=512 required)

    // workspace carve-up (256B aligned)
    char* ws = (char*)d_ws;
    size_t off = 0;
    auto alloc = [&](size_t bytes) -> void* {
        off = (off + 255) & ~(size_t)255;
        void* p = ws + off;
        off += bytes;
        return p;
    };
    unsigned short* feat_src_bf = (unsigned short*)alloc((size_t)N * HF * sizeof(unsigned short));
    float* el      = (float*)alloc((size_t)N * NH * sizeof(float));
    float* er      = (float*)alloc((size_t)N * NH * sizeof(float));
    int*   bcount  = (int*)  alloc((size_t)(nbuck + 1) * sizeof(int));
    int*   bbase   = (int*)  alloc((size_t)(nbuck + 1) * sizeof(int));
    int*   gcursor = (int*)  alloc((size_t)nbuck * sizeof(int));
    int*   offsets = (int*)  alloc((size_t)(N + 1) * sizeof(int));
    uint2* gpairs  = (uint2*)alloc((size_t)E * sizeof(uint2));
    int*   slot    = (int*)  alloc((size_t)E * sizeof(int));

    hipMemsetAsync(bcount, 0, (size_t)(nbuck + 1) * sizeof(int), stream);

    gat_gemm_el_er<<<(N + GEMM_ROWS - 1) / GEMM_ROWS, 128, 0, stream>>>(
        feat, W, attn_l, attn_r, feat_src_bf, el, er, N);

    const int nwg1   = 128;
    const int chunk1 = (E + nwg1 - 1) / nwg1;
    gat_bucket_hist<<<nwg1, 256, 0, stream>>>(dst, bcount, E, nbuck, chunk1);
    gat_bucket_scan<<<1, 512, 0, stream>>>(bcount, bbase, gcursor, offsets, N, E, nbuck);
    gat_bin<<<(E + BIN_CHUNK - 1) / BIN_CHUNK, 256, 0, stream>>>(src, dst, gcursor, gpairs, E);
    gat_fine<<<nbuck, 256, 0, stream>>>(gpairs, bbase, offsets, slot, N);

    gat_aggregate<<<N, 64, 0, stream>>>(feat_src_bf, el, er, offsets, slot, bias, out, N);
}

// Round 4
// 174.551 us; speedup vs baseline: 2.4312x; 1.3313x over previous
//
#include <hip/hip_runtime.h>

#define IN_F 128
#define HF   128   // H*F
#define NH   4
#define NF   32

#define NPB       256   // nodes per coarse bucket
#define NPB_SHIFT 8
#define BIN_CHUNK 4096  // edges per binning workgroup

typedef __attribute__((ext_vector_type(8))) short short8v;  // 8 bf16 (4 VGPRs)
typedef __attribute__((ext_vector_type(4))) float f32x4;    // MFMA acc

// bf16 helpers (bit-level, RTN)
__device__ __forceinline__ unsigned short f32_to_bf16_rtn(float f) {
    unsigned int u = __float_as_uint(f);
    u += 0x7fffu + ((u >> 16) & 1u);
    return (unsigned short)(u >> 16);
}

// ---------------- K0: pack W into MFMA B-fragment layout ----------------
// wfrag[(nt*4+kb)*64 + lane] = 8 bf16: j -> W[(kb*32 + 8*(lane>>4) + j)*128 + nt*16 + (lane&15)]
__global__ void __launch_bounds__(256)
gat_wfrag(const float* __restrict__ W, short8v* __restrict__ wfrag) {
    const int entry = blockIdx.x * 256 + threadIdx.x;   // 0..2047
    const int lane = entry & 63;
    const int kb   = (entry >> 6) & 3;
    const int nt   = entry >> 8;
    const int k0   = kb * 32 + (lane >> 4) * 8;
    const int col  = nt * 16 + (lane & 15);
    short8v s;
    #pragma unroll
    for (int j = 0; j < 8; ++j)
        s[j] = (short)f32_to_bf16_rtn(W[(k0 + j) * HF + col]);
    wfrag[entry] = s;
}

// ---------------- K1: MFMA GEMM (feat @ W) + el/er epilogue ----------------
// 256 threads = 4 waves; wave computes 16 rows x 128 cols; block = 64 rows.
__global__ void __launch_bounds__(256)
gat_gemm_mfma(const float* __restrict__ feat, const short8v* __restrict__ wfrag,
              const float* __restrict__ attn_l, const float* __restrict__ attn_r,
              unsigned short* __restrict__ feat_src_bf,
              float* __restrict__ el, float* __restrict__ er, int N) {
    const int lane = threadIdx.x & 63;
    const int wave = threadIdx.x >> 6;
    const int row0 = blockIdx.x * 64 + wave * 16;
    const int m = lane & 15;        // A row / D col within tile
    const int g = lane >> 4;        // k-group / D row group
    const int arow = min(row0 + m, N - 1);

    // A fragments for the whole K=128 strip: lane holds A[m][kb*32 + g*8 + j]
    short8v aw[4];
    const float* fbase = feat + (size_t)arow * IN_F;
    #pragma unroll
    for (int kb = 0; kb < 4; ++kb) {
        const float4* p = (const float4*)(fbase + kb * 32 + g * 8);
        float4 f0 = p[0];
        float4 f1 = p[1];
        short8v a;
        a[0] = (short)f32_to_bf16_rtn(f0.x);
        a[1] = (short)f32_to_bf16_rtn(f0.y);
        a[2] = (short)f32_to_bf16_rtn(f0.z);
        a[3] = (short)f32_to_bf16_rtn(f0.w);
        a[4] = (short)f32_to_bf16_rtn(f1.x);
        a[5] = (short)f32_to_bf16_rtn(f1.y);
        a[6] = (short)f32_to_bf16_rtn(f1.z);
        a[7] = (short)f32_to_bf16_rtn(f1.w);
        aw[kb] = a;
    }

    f32x4 acc[8];
    #pragma unroll
    for (int nt = 0; nt < 8; ++nt) acc[nt] = (f32x4){0.f, 0.f, 0.f, 0.f};

    const short8v* wf = wfrag + lane;
    #pragma unroll
    for (int nt = 0; nt < 8; ++nt) {
        #pragma unroll
        for (int kb = 0; kb < 4; ++kb) {
            short8v bw = wf[(nt * 4 + kb) * 64];
            acc[nt] = __builtin_amdgcn_mfma_f32_16x16x32_bf16(aw[kb], bw, acc[nt], 0, 0, 0);
        }
    }

    // attn vectors for this lane's columns
    float al[8], ar[8];
    #pragma unroll
    for (int nt = 0; nt < 8; ++nt) {
        al[nt] = attn_l[nt * 16 + m];
        ar[nt] = attn_r[nt * 16 + m];
    }

    // epilogue: D row = row0 + 4*g + r, col = nt*16 + m
    #pragma unroll
    for (int r = 0; r < 4; ++r) {
        const int row = row0 + 4 * g + r;
        const bool valid = (row < N);
        if (valid) {
            #pragma unroll
            for (int nt = 0; nt < 8; ++nt)
                feat_src_bf[(size_t)row * HF + nt * 16 + m] = f32_to_bf16_rtn(acc[nt][r]);
        }
        float pl[NH], pr[NH];
        #pragma unroll
        for (int h = 0; h < NH; ++h) {
            pl[h] = acc[2 * h][r] * al[2 * h] + acc[2 * h + 1][r] * al[2 * h + 1];
            pr[h] = acc[2 * h][r] * ar[2 * h] + acc[2 * h + 1][r] * ar[2 * h + 1];
        }
        #pragma unroll
        for (int mask = 1; mask <= 8; mask <<= 1) {
            #pragma unroll
            for (int h = 0; h < NH; ++h) {
                pl[h] += __shfl_xor(pl[h], mask);
                pr[h] += __shfl_xor(pr[h], mask);
            }
        }
        if (valid && m == 0) {
            #pragma unroll
            for (int h = 0; h < NH; ++h) {
                el[row * NH + h] = pl[h];
                er[row * NH + h] = pr[h];
            }
        }
    }
}

// ---------------- CSR build via 2-level binning ----------------
__global__ void __launch_bounds__(256)
gat_bucket_hist(const int* __restrict__ dst, int* __restrict__ bcount,
                int E, int nbuck, int chunk) {
    __shared__ int h[512];
    const int t = threadIdx.x;
    for (int i = t; i < 512; i += 256) h[i] = 0;
    __syncthreads();
    const int e0 = blockIdx.x * chunk;
    const int e1 = min(e0 + chunk, E);
    for (int e = e0 + t; e < e1; e += 256)
        atomicAdd(&h[dst[e] >> NPB_SHIFT], 1);
    __syncthreads();
    for (int b = t; b < nbuck; b += 256)
        if (h[b]) atomicAdd(&bcount[b], h[b]);
}

__global__ void __launch_bounds__(512)
gat_bucket_scan(const int* __restrict__ bcount, int* __restrict__ bbase,
                int* __restrict__ gcursor, int* __restrict__ offsets,
                int N, int E, int nbuck) {
    __shared__ int buf[512];
    const int t = threadIdx.x;
    int v = (t < nbuck) ? bcount[t] : 0;
    buf[t] = v;
    __syncthreads();
    for (int off = 1; off < 512; off <<= 1) {
        int x = (t >= off) ? buf[t - off] : 0;
        __syncthreads();
        buf[t] += x;
        __syncthreads();
    }
    if (t < nbuck) {
        int base = buf[t] - v;
        bbase[t]   = base;
        gcursor[t] = base;
    }
    if (t == 0) {
        bbase[nbuck] = E;
        offsets[N]   = E;
    }
}

__global__ void __launch_bounds__(256)
gat_bin(const int* __restrict__ src, const int* __restrict__ dst,
        int* __restrict__ gcursor, uint2* __restrict__ gpairs, int E) {
    __shared__ uint2 stage[BIN_CHUNK];        // 32KB
    __shared__ int hist[512];
    __shared__ int sc[512];
    __shared__ int basew[512];
    __shared__ int cur[512];
    const int t = threadIdx.x;
    for (int i = t; i < 512; i += 256) hist[i] = 0;
    __syncthreads();
    const int e0  = blockIdx.x * BIN_CHUNK;
    const int cnt = min(BIN_CHUNK, E - e0);
    for (int i = t; i < cnt; i += 256)
        atomicAdd(&hist[dst[e0 + i] >> NPB_SHIFT], 1);
    __syncthreads();
    sc[t]       = hist[t];
    sc[t + 256] = hist[t + 256];
    __syncthreads();
    for (int off = 1; off < 512; off <<= 1) {
        int x0 = (t >= off) ? sc[t - off] : 0;
        int x1 = sc[t + 256 - off];
        __syncthreads();
        sc[t]       += x0;
        sc[t + 256] += x1;
        __syncthreads();
    }
    for (int b = t; b < 512; b += 256) {
        int c  = hist[b];
        int ex = sc[b] - c;
        cur[b] = ex;
        basew[b] = c ? atomicAdd(&gcursor[b], c) : 0;
    }
    __syncthreads();
    for (int i = t; i < cnt; i += 256) {
        unsigned s = (unsigned)src[e0 + i];
        unsigned d = (unsigned)dst[e0 + i];
        int p = atomicAdd(&cur[d >> NPB_SHIFT], 1);
        stage[p] = make_uint2(s, d);
    }
    __syncthreads();
    for (int j = t; j < cnt; j += 256) {
        uint2 pr = stage[j];
        int b  = (int)(pr.y >> NPB_SHIFT);
        int ex = sc[b] - hist[b];
        gpairs[basew[b] + (j - ex)] = pr;
    }
}

__global__ void __launch_bounds__(256)
gat_fine(const uint2* __restrict__ gpairs, const int* __restrict__ bbase,
         int* __restrict__ offsets, int* __restrict__ slot, int N) {
    __shared__ int h[NPB];
    __shared__ int buf[NPB];
    __shared__ int cur[NPB];
    const int b     = blockIdx.x;
    const int node0 = b << NPB_SHIFT;
    const int t     = threadIdx.x;          // 256
    const int beg = bbase[b];
    const int end = bbase[b + 1];
    h[t] = 0;
    __syncthreads();
    for (int i = beg + t; i < end; i += 256)
        atomicAdd(&h[(int)gpairs[i].y - node0], 1);
    __syncthreads();
    int v = h[t];
    buf[t] = v;
    __syncthreads();
    for (int off = 1; off < 256; off <<= 1) {
        int x = (t >= off) ? buf[t - off] : 0;
        __syncthreads();
        buf[t] += x;
        __syncthreads();
    }
    int ex = buf[t] - v;
    if (node0 + t < N) offsets[node0 + t] = beg + ex;
    cur[t] = ex;
    __syncthreads();
    for (int i = beg + t; i < end; i += 256) {
        uint2 pr = gpairs[i];
        int p = atomicAdd(&cur[(int)pr.y - node0], 1);
        slot[beg + p] = (int)pr.x;
    }
}

// ---------------- per-dst-node softmax + weighted aggregation ----------------
__global__ void __launch_bounds__(64)
gat_aggregate(const unsigned short* __restrict__ feat_src_bf,
              const float* __restrict__ el,
              const float* __restrict__ er, const int* __restrict__ offsets,
              const int* __restrict__ slot, const float* __restrict__ bias,
              float* __restrict__ out, int N) {
    const int node = blockIdx.x;
    const int lane = threadIdx.x;
    const int start = offsets[node];
    const int end   = offsets[node + 1];

    const float er0 = er[node * NH + 0];
    const float er1 = er[node * NH + 1];
    const float er2 = er[node * NH + 2];
    const float er3 = er[node * NH + 3];

    float d0 = 0.f, d1 = 0.f, d2 = 0.f, d3 = 0.f;
    for (int i = start + lane; i < end; i += 64) {
        int s = slot[i];
        float4 ev = *(const float4*)(el + s * NH);
        float x0 = ev.x + er0; d0 += __expf(fmaxf(x0, 0.2f * x0));
        float x1 = ev.y + er1; d1 += __expf(fmaxf(x1, 0.2f * x1));
        float x2 = ev.z + er2; d2 += __expf(fmaxf(x2, 0.2f * x2));
        float x3 = ev.w + er3; d3 += __expf(fmaxf(x3, 0.2f * x3));
    }
    #pragma unroll
    for (int m = 32; m >= 1; m >>= 1) {
        d0 += __shfl_xor(d0, m);
        d1 += __shfl_xor(d1, m);
        d2 += __shfl_xor(d2, m);
        d3 += __shfl_xor(d3, m);
    }

    const int h = lane >> 4;
    const float er_h = (h == 0) ? er0 : (h == 1) ? er1 : (h == 2) ? er2 : er3;
    const float den  = (h == 0) ? d0  : (h == 1) ? d1  : (h == 2) ? d2  : d3;
    const float inv  = 1.0f / fmaxf(den, 1e-9f);

    float ax = 0.f, ay = 0.f;
    const unsigned short* fsp = feat_src_bf + 2 * lane;
    int i = start;
    for (; i + 1 < end; i += 2) {
        int s0 = slot[i];
        int s1 = slot[i + 1];
        float e0 = el[s0 * NH + h] + er_h;
        float e1 = el[s1 * NH + h] + er_h;
        unsigned int u0 = *(const unsigned int*)(fsp + (size_t)s0 * HF);
        unsigned int u1 = *(const unsigned int*)(fsp + (size_t)s1 * HF);
        float w0 = __expf(fmaxf(e0, 0.2f * e0)) * inv;
        float w1 = __expf(fmaxf(e1, 0.2f * e1)) * inv;
        ax += w0 * __uint_as_float(u0 << 16) + w1 * __uint_as_float(u1 << 16);
        ay += w0 * __uint_as_float(u0 & 0xffff0000u) + w1 * __uint_as_float(u1 & 0xffff0000u);
    }
    if (i < end) {
        int s0 = slot[i];
        float e0 = el[s0 * NH + h] + er_h;
        unsigned int u0 = *(const unsigned int*)(fsp + (size_t)s0 * HF);
        float w0 = __expf(fmaxf(e0, 0.2f * e0)) * inv;
        ax += w0 * __uint_as_float(u0 << 16);
        ay += w0 * __uint_as_float(u0 & 0xffff0000u);
    }
    float2 b2 = *(const float2*)(bias + 2 * lane);
    out[node * HF + 2 * lane]     = ax + b2.x;
    out[node * HF + 2 * lane + 1] = ay + b2.y;
}

extern "C" void kernel_launch(void* const* d_in, const int* in_sizes, int n_in,
                              void* d_out, int out_size, void* d_ws, size_t ws_size,
                              hipStream_t stream) {
    const float* feat   = (const float*)d_in[0];
    const float* W      = (const float*)d_in[1];
    const float* attn_l = (const float*)d_in[2];
    const float* attn_r = (const float*)d_in[3];
    const float* bias   = (const float*)d_in[4];
    const int*   src    = (const int*)d_in[5];
    const int*   dst    = (const int*)d_in[6];
    float* out = (float*)d_out;

    const int N = in_sizes[0] / IN_F;
    const int E = in_sizes[5];
    const int nbuck = (N + NPB - 1) / NPB;      // 391 for N=100000 (<=512 required)

    // workspace carve-up (256B aligned)
    char* ws = (char*)d_ws;
    size_t off = 0;
    auto alloc = [&](size_t bytes) -> void* {
        off = (off + 255) & ~(size_t)255;
        void* p = ws + off;
        off += bytes;
        return p;
    };
    unsigned short* feat_src_bf = (unsigned short*)alloc((size_t)N * HF * sizeof(unsigned short));
    float* el      = (float*)alloc((size_t)N * NH * sizeof(float));
    float* er      = (float*)alloc((size_t)N * NH * sizeof(float));
    int*   bcount  = (int*)  alloc((size_t)(nbuck + 1) * sizeof(int));
    int*   bbase   = (int*)  alloc((size_t)(nbuck + 1) * sizeof(int));
    int*   gcursor = (int*)  alloc((size_t)nbuck * sizeof(int));
    int*   offsets = (int*)  alloc((size_t)(N + 1) * sizeof(int));
    uint2* gpairs  = (uint2*)alloc((size_t)E * sizeof(uint2));
    int*   slot    = (int*)  alloc((size_t)E * sizeof(int));
    short8v* wfrag = (short8v*)alloc((size_t)2048 * sizeof(short8v));   // 32KB

    hipMemsetAsync(bcount, 0, (size_t)(nbuck + 1) * sizeof(int), stream);

    gat_wfrag<<<8, 256, 0, stream>>>(W, wfrag);
    gat_gemm_mfma<<<(N + 63) / 64, 256, 0, stream>>>(
        feat, wfrag, attn_l, attn_r, feat_src_bf, el, er, N);

    const int nwg1   = 128;
    const int chunk1 = (E + nwg1 - 1) / nwg1;
    gat_bucket_hist<<<nwg1, 256, 0, stream>>>(dst, bcount, E, nbuck, chunk1);
    gat_bucket_scan<<<1, 512, 0, stream>>>(bcount, bbase, gcursor, offsets, N, E, nbuck);
    gat_bin<<<(E + BIN_CHUNK - 1) / BIN_CHUNK, 256, 0, stream>>>(src, dst, gcursor, gpairs, E);
    gat_fine<<<nbuck, 256, 0, stream>>>(gpairs, bbase, offsets, slot, N);

    gat_aggregate<<<N, 64, 0, stream>>>(feat_src_bf, el, er, offsets, slot, bias, out, N);
}

// Round 5
// 170.259 us; speedup vs baseline: 2.4925x; 1.0252x over previous
//
#include <hip/hip_runtime.h>

#define IN_F 128
#define HF   128   // H*F
#define NH   4
#define NF   32

#define NPB       256   // nodes per coarse bucket
#define NPB_SHIFT 8
#define BIN_CHUNK 4096  // edges per binning workgroup

typedef __attribute__((ext_vector_type(8))) short short8v;  // 8 bf16 (4 VGPRs)
typedef __attribute__((ext_vector_type(4))) float f32x4;    // MFMA acc

// bf16 helpers (bit-level, RTN)
__device__ __forceinline__ unsigned short f32_to_bf16_rtn(float f) {
    unsigned int u = __float_as_uint(f);
    u += 0x7fffu + ((u >> 16) & 1u);
    return (unsigned short)(u >> 16);
}
__device__ __forceinline__ float bf16_lo(unsigned int u) { return __uint_as_float(u << 16); }
__device__ __forceinline__ float bf16_hi(unsigned int u) { return __uint_as_float(u & 0xffff0000u); }

// ---------------- K0: pack W into MFMA B-fragment layout ----------------
// wfrag[(nt*4+kb)*64 + lane] = 8 bf16: j -> W[(kb*32 + 8*(lane>>4) + j)*128 + nt*16 + (lane&15)]
__global__ void __launch_bounds__(256)
gat_wfrag(const float* __restrict__ W, short8v* __restrict__ wfrag) {
    const int entry = blockIdx.x * 256 + threadIdx.x;   // 0..2047
    const int lane = entry & 63;
    const int kb   = (entry >> 6) & 3;
    const int nt   = entry >> 8;
    const int k0   = kb * 32 + (lane >> 4) * 8;
    const int col  = nt * 16 + (lane & 15);
    short8v s;
    #pragma unroll
    for (int j = 0; j < 8; ++j)
        s[j] = (short)f32_to_bf16_rtn(W[(k0 + j) * HF + col]);
    wfrag[entry] = s;
}

// ---------------- K1: MFMA GEMM (feat @ W) + el/er epilogue ----------------
// 256 threads = 4 waves; block computes 64 rows x 128 cols. A and W staged in LDS.
__global__ void __launch_bounds__(256)
gat_gemm_mfma(const float* __restrict__ feat, const short8v* __restrict__ wfrag,
              const float* __restrict__ attn_l, const float* __restrict__ attn_r,
              unsigned short* __restrict__ feat_src_bf,
              float* __restrict__ el, float* __restrict__ er, int N) {
    __shared__ unsigned short a_lds[8192];    // 16KB: A fragments, frag-major
    __shared__ unsigned short w_lds[16384];   // 32KB: W fragments, entry-major
    const int t    = threadIdx.x;
    const int lane = t & 63;
    const int wave = t >> 6;
    const int row0b = blockIdx.x * 64;

    // stage W (32KB, coalesced 16B/thread x 8)
    {
        const uint4* wsrc = (const uint4*)wfrag;
        uint4* wdst = (uint4*)w_lds;
        #pragma unroll
        for (int i = 0; i < 8; ++i)
            wdst[i * 256 + t] = wsrc[i * 256 + t];
    }
    // stage A: 64 rows x 128 f32, coalesced float4 loads -> bf16 fragment-major LDS
    #pragma unroll
    for (int i = 0; i < 8; ++i) {
        int idx = i * 256 + t;           // float4 index, 0..2047
        int row = idx >> 5;
        int c4  = idx & 31;
        int srow = min(row0b + row, N - 1);
        float4 f = *(const float4*)(feat + (size_t)srow * IN_F + c4 * 4);
        unsigned int lo = ((unsigned int)f32_to_bf16_rtn(f.y) << 16) | f32_to_bf16_rtn(f.x);
        unsigned int hi = ((unsigned int)f32_to_bf16_rtn(f.w) << 16) | f32_to_bf16_rtn(f.z);
        int kb = c4 >> 3, g = (c4 >> 1) & 3, half = c4 & 1;
        int wv = row >> 4, m = row & 15;
        unsigned int* p = (unsigned int*)a_lds;
        int u = (wv * 4096 + kb * 1024 + g * 256 + m * 16 + half * 8) >> 2;
        p[u]     = lo;
        p[u + 1] = hi;
    }
    __syncthreads();

    const int m = lane & 15;
    const int g = lane >> 4;
    short8v aw[4];
    #pragma unroll
    for (int kb = 0; kb < 4; ++kb)
        aw[kb] = *(const short8v*)&a_lds[wave * 2048 + kb * 512 + g * 128 + m * 8];

    f32x4 acc[8];
    #pragma unroll
    for (int nt = 0; nt < 8; ++nt) acc[nt] = (f32x4){0.f, 0.f, 0.f, 0.f};

    #pragma unroll
    for (int nt = 0; nt < 8; ++nt) {
        #pragma unroll
        for (int kb = 0; kb < 4; ++kb) {
            short8v bw = *(const short8v*)&w_lds[((nt * 4 + kb) * 64 + lane) * 8];
            acc[nt] = __builtin_amdgcn_mfma_f32_16x16x32_bf16(aw[kb], bw, acc[nt], 0, 0, 0);
        }
    }

    float al[8], ar[8];
    #pragma unroll
    for (int nt = 0; nt < 8; ++nt) {
        al[nt] = attn_l[nt * 16 + m];
        ar[nt] = attn_r[nt * 16 + m];
    }

    // epilogue: D row = row0b + wave*16 + 4*g + r, col = nt*16 + m
    #pragma unroll
    for (int r = 0; r < 4; ++r) {
        const int row = row0b + wave * 16 + 4 * g + r;
        const bool valid = (row < N);
        if (valid) {
            #pragma unroll
            for (int nt = 0; nt < 8; ++nt)
                feat_src_bf[(size_t)row * HF + nt * 16 + m] = f32_to_bf16_rtn(acc[nt][r]);
        }
        float pl[NH], pr[NH];
        #pragma unroll
        for (int h = 0; h < NH; ++h) {
            pl[h] = acc[2 * h][r] * al[2 * h] + acc[2 * h + 1][r] * al[2 * h + 1];
            pr[h] = acc[2 * h][r] * ar[2 * h] + acc[2 * h + 1][r] * ar[2 * h + 1];
        }
        #pragma unroll
        for (int mask = 1; mask <= 8; mask <<= 1) {
            #pragma unroll
            for (int h = 0; h < NH; ++h) {
                pl[h] += __shfl_xor(pl[h], mask);
                pr[h] += __shfl_xor(pr[h], mask);
            }
        }
        if (valid && m == 0) {
            *(float4*)(el + (size_t)row * NH) = make_float4(pl[0], pl[1], pl[2], pl[3]);
            *(float4*)(er + (size_t)row * NH) = make_float4(pr[0], pr[1], pr[2], pr[3]);
        }
    }
}

// ---------------- CSR build via 2-level binning ----------------
__global__ void __launch_bounds__(256)
gat_bucket_hist(const int* __restrict__ dst, int* __restrict__ bcount,
                int E, int nbuck, int chunk) {
    __shared__ int h[512];
    const int t = threadIdx.x;
    for (int i = t; i < 512; i += 256) h[i] = 0;
    __syncthreads();
    const int e0 = blockIdx.x * chunk;
    const int e1 = min(e0 + chunk, E);
    for (int e = e0 + t; e < e1; e += 256)
        atomicAdd(&h[dst[e] >> NPB_SHIFT], 1);
    __syncthreads();
    for (int b = t; b < nbuck; b += 256)
        if (h[b]) atomicAdd(&bcount[b], h[b]);
}

__global__ void __launch_bounds__(512)
gat_bucket_scan(const int* __restrict__ bcount, int* __restrict__ bbase,
                int* __restrict__ gcursor, int* __restrict__ offsets,
                int N, int E, int nbuck) {
    __shared__ int buf[512];
    const int t = threadIdx.x;
    int v = (t < nbuck) ? bcount[t] : 0;
    buf[t] = v;
    __syncthreads();
    for (int off = 1; off < 512; off <<= 1) {
        int x = (t >= off) ? buf[t - off] : 0;
        __syncthreads();
        buf[t] += x;
        __syncthreads();
    }
    if (t < nbuck) {
        int base = buf[t] - v;
        bbase[t]   = base;
        gcursor[t] = base;
    }
    if (t == 0) {
        bbase[nbuck] = E;
        offsets[N]   = E;
    }
}

__global__ void __launch_bounds__(256)
gat_bin(const int* __restrict__ src, const int* __restrict__ dst,
        int* __restrict__ gcursor, uint2* __restrict__ gpairs, int E) {
    __shared__ uint2 stage[BIN_CHUNK];        // 32KB
    __shared__ int hist[512];
    __shared__ int sc[512];
    __shared__ int basew[512];
    __shared__ int cur[512];
    const int t = threadIdx.x;
    for (int i = t; i < 512; i += 256) hist[i] = 0;
    __syncthreads();
    const int e0  = blockIdx.x * BIN_CHUNK;
    const int cnt = min(BIN_CHUNK, E - e0);
    for (int i = t; i < cnt; i += 256)
        atomicAdd(&hist[dst[e0 + i] >> NPB_SHIFT], 1);
    __syncthreads();
    sc[t]       = hist[t];
    sc[t + 256] = hist[t + 256];
    __syncthreads();
    for (int off = 1; off < 512; off <<= 1) {
        int x0 = (t >= off) ? sc[t - off] : 0;
        int x1 = sc[t + 256 - off];
        __syncthreads();
        sc[t]       += x0;
        sc[t + 256] += x1;
        __syncthreads();
    }
    for (int b = t; b < 512; b += 256) {
        int c  = hist[b];
        int ex = sc[b] - c;
        cur[b] = ex;
        basew[b] = c ? atomicAdd(&gcursor[b], c) : 0;
    }
    __syncthreads();
    for (int i = t; i < cnt; i += 256) {
        unsigned s = (unsigned)src[e0 + i];
        unsigned d = (unsigned)dst[e0 + i];
        int p = atomicAdd(&cur[d >> NPB_SHIFT], 1);
        stage[p] = make_uint2(s, d);
    }
    __syncthreads();
    for (int j = t; j < cnt; j += 256) {
        uint2 pr = stage[j];
        int b  = (int)(pr.y >> NPB_SHIFT);
        int ex = sc[b] - hist[b];
        gpairs[basew[b] + (j - ex)] = pr;
    }
}

__global__ void __launch_bounds__(256)
gat_fine(const uint2* __restrict__ gpairs, const int* __restrict__ bbase,
         int* __restrict__ offsets, int* __restrict__ slot, int N) {
    __shared__ int h[NPB];
    __shared__ int buf[NPB];
    __shared__ int cur[NPB];
    const int b     = blockIdx.x;
    const int node0 = b << NPB_SHIFT;
    const int t     = threadIdx.x;          // 256
    const int beg = bbase[b];
    const int end = bbase[b + 1];
    h[t] = 0;
    __syncthreads();
    for (int i = beg + t; i < end; i += 256)
        atomicAdd(&h[(int)gpairs[i].y - node0], 1);
    __syncthreads();
    int v = h[t];
    buf[t] = v;
    __syncthreads();
    for (int off = 1; off < 256; off <<= 1) {
        int x = (t >= off) ? buf[t - off] : 0;
        __syncthreads();
        buf[t] += x;
        __syncthreads();
    }
    int ex = buf[t] - v;
    if (node0 + t < N) offsets[node0 + t] = beg + ex;
    cur[t] = ex;
    __syncthreads();
    for (int i = beg + t; i < end; i += 256) {
        uint2 pr = gpairs[i];
        int p = atomicAdd(&cur[(int)pr.y - node0], 1);
        slot[beg + p] = (int)pr.x;
    }
}

// ---------------- single-pass softmax + aggregation ----------------
// 256 threads = 4 waves; wave w handles node blockIdx.x*4+w. Deferred
// normalization: out = (sum ex*feat)/denom. No inter-wave sync (wave-local LDS).
__global__ void __launch_bounds__(256)
gat_aggregate(const unsigned short* __restrict__ feat_src_bf,
              const float* __restrict__ el, const float* __restrict__ er,
              const int* __restrict__ offsets, const int* __restrict__ slot,
              const float* __restrict__ bias, float* __restrict__ out, int N) {
    __shared__ int   ss[4][64];
    __shared__ float exs[4][256];
    const int lane = threadIdx.x & 63;
    const int wave = threadIdx.x >> 6;
    const int node = blockIdx.x * 4 + wave;
    if (node >= N) return;
    const int start = offsets[node];
    const int end   = offsets[node + 1];
    const int hm = lane >> 4;

    const float4 er4 = *(const float4*)(er + (size_t)node * NH);
    float d0 = 0.f, d1 = 0.f, d2 = 0.f, d3 = 0.f;
    float ax = 0.f, ay = 0.f;
    const unsigned short* fsp = feat_src_bf + 2 * lane;
    int*   ssw = ss[wave];
    float* exw = exs[wave];

    for (int c = start; c < end; c += 64) {
        int idx = c + lane;
        bool vld = idx < end;
        int s_l = vld ? slot[idx] : 0;
        float4 ev = make_float4(0.f, 0.f, 0.f, 0.f);
        if (vld) ev = *(const float4*)(el + (size_t)s_l * NH);
        float x0 = ev.x + er4.x; x0 = fmaxf(x0, 0.2f * x0);
        float x1 = ev.y + er4.y; x1 = fmaxf(x1, 0.2f * x1);
        float x2 = ev.z + er4.z; x2 = fmaxf(x2, 0.2f * x2);
        float x3 = ev.w + er4.w; x3 = fmaxf(x3, 0.2f * x3);
        float e0 = vld ? __expf(x0) : 0.f;
        float e1 = vld ? __expf(x1) : 0.f;
        float e2 = vld ? __expf(x2) : 0.f;
        float e3 = vld ? __expf(x3) : 0.f;
        d0 += e0; d1 += e1; d2 += e2; d3 += e3;
        ssw[lane] = s_l;
        *(float4*)&exw[lane * 4] = make_float4(e0, e1, e2, e3);
        asm volatile("" ::: "memory");   // order LDS write before wave-local reads
        const int n = min(64, end - c);
        int j = 0;
        for (; j + 1 < n; j += 2) {
            int sA = ssw[j];
            int sB = ssw[j + 1];
            float wA = exw[j * 4 + hm];
            float wB = exw[j * 4 + 4 + hm];
            unsigned int uA = *(const unsigned int*)(fsp + (size_t)sA * HF);
            unsigned int uB = *(const unsigned int*)(fsp + (size_t)sB * HF);
            ax += wA * bf16_lo(uA) + wB * bf16_lo(uB);
            ay += wA * bf16_hi(uA) + wB * bf16_hi(uB);
        }
        if (j < n) {
            int sA = ssw[j];
            float wA = exw[j * 4 + hm];
            unsigned int uA = *(const unsigned int*)(fsp + (size_t)sA * HF);
            ax += wA * bf16_lo(uA);
            ay += wA * bf16_hi(uA);
        }
        asm volatile("" ::: "memory");   // keep next chunk's writes after reads
    }

    // denominator: sum over all 64 lanes. First across head-groups, then within.
    #pragma unroll
    for (int msk = 16; msk <= 32; msk <<= 1) {
        d0 += __shfl_xor(d0, msk);
        d1 += __shfl_xor(d1, msk);
        d2 += __shfl_xor(d2, msk);
        d3 += __shfl_xor(d3, msk);
    }
    float dh = (hm == 0) ? d0 : (hm == 1) ? d1 : (hm == 2) ? d2 : d3;
    #pragma unroll
    for (int msk = 1; msk <= 8; msk <<= 1) dh += __shfl_xor(dh, msk);
    const float inv = 1.0f / fmaxf(dh, 1e-9f);

    float2 b2 = *(const float2*)(bias + 2 * lane);
    float2 o;
    o.x = ax * inv + b2.x;
    o.y = ay * inv + b2.y;
    *(float2*)(out + (size_t)node * HF + 2 * lane) = o;
}

extern "C" void kernel_launch(void* const* d_in, const int* in_sizes, int n_in,
                              void* d_out, int out_size, void* d_ws, size_t ws_size,
                              hipStream_t stream) {
    const float* feat   = (const float*)d_in[0];
    const float* W      = (const float*)d_in[1];
    const float* attn_l = (const float*)d_in[2];
    const float* attn_r = (const float*)d_in[3];
    const float* bias   = (const float*)d_in[4];
    const int*   src    = (const int*)d_in[5];
    const int*   dst    = (const int*)d_in[6];
    float* out = (float*)d_out;

    const int N = in_sizes[0] / IN_F;
    const int E = in_sizes[5];
    const int nbuck = (N + NPB - 1) / NPB;      // 391 for N=100000 (<=512 required)

    // workspace carve-up (256B aligned)
    char* ws = (char*)d_ws;
    size_t off = 0;
    auto alloc = [&](size_t bytes) -> void* {
        off = (off + 255) & ~(size_t)255;
        void* p = ws + off;
        off += bytes;
        return p;
    };
    unsigned short* feat_src_bf = (unsigned short*)alloc((size_t)N * HF * sizeof(unsigned short));
    float* el      = (float*)alloc((size_t)N * NH * sizeof(float));
    float* er      = (float*)alloc((size_t)N * NH * sizeof(float));
    int*   bcount  = (int*)  alloc((size_t)(nbuck + 1) * sizeof(int));
    int*   bbase   = (int*)  alloc((size_t)(nbuck + 1) * sizeof(int));
    int*   gcursor = (int*)  alloc((size_t)nbuck * sizeof(int));
    int*   offsets = (int*)  alloc((size_t)(N + 1) * sizeof(int));
    uint2* gpairs  = (uint2*)alloc((size_t)E * sizeof(uint2));
    int*   slot    = (int*)  alloc((size_t)E * sizeof(int));
    short8v* wfrag = (short8v*)alloc((size_t)2048 * sizeof(short8v));   // 32KB

    hipMemsetAsync(bcount, 0, (size_t)(nbuck + 1) * sizeof(int), stream);

    gat_wfrag<<<8, 256, 0, stream>>>(W, wfrag);
    gat_gemm_mfma<<<(N + 63) / 64, 256, 0, stream>>>(
        feat, wfrag, attn_l, attn_r, feat_src_bf, el, er, N);

    const int nwg1   = 128;
    const int chunk1 = (E + nwg1 - 1) / nwg1;
    gat_bucket_hist<<<nwg1, 256, 0, stream>>>(dst, bcount, E, nbuck, chunk1);
    gat_bucket_scan<<<1, 512, 0, stream>>>(bcount, bbase, gcursor, offsets, N, E, nbuck);
    gat_bin<<<(E + BIN_CHUNK - 1) / BIN_CHUNK, 256, 0, stream>>>(src, dst, gcursor, gpairs, E);
    gat_fine<<<nbuck, 256, 0, stream>>>(gpairs, bbase, offsets, slot, N);

    gat_aggregate<<<(N + 3) / 4, 256, 0, stream>>>(feat_src_bf, el, er, offsets, slot, bias, out, N);
}